// Round 11
// baseline (187.465 us; speedup 1.0000x reference)
//
#include <hip/hip_runtime.h>
#include <hip/hip_fp16.h>

#define N_NODES 50000
#define N_EDGES 1600000
#define F_IN 8
#define F_OUT 12
#define PERIODS 6
#define FP 48                      // F_IN * PERIODS
#define BKT_SH 7                   // 128 nodes per bucket
#define BKT_N 128
#define NBKT ((N_NODES + BKT_N - 1) / BKT_N)   // 391
#define CHK 4096                   // edges per scatter block (4/thread at 1024 threads)
#define NCHK ((N_EDGES + CHK - 1) / CHK)       // 391
#define SEG_CAP 4736               // per-bucket part/stage capacity (mean 4092, +10 sigma)
#define SEG_AL  5120               // per-bucket csr stride: 4736 + 128*3 (4-align pad, exact)
#define DEG_SCALE 16777216.0f      // 2^24 fixed point for degree (u32 low word)
#define DEG_INV   5.9604644775390625e-8f

typedef unsigned int u32x4 __attribute__((ext_vector_type(4)));

// ---- pass 1: fused histogram + reservation + scatter (bucketed) ----
// part entry: hi32 = fp32 ew bits, lo32 = (dlocal&127)<<24 | src   (src < 2^16)
// PLAIN stores: per-(block,bucket) runs assemble into full lines in the writer's
// L2 within one block's burst (round-2: NT stores 6.5x write amp; round-5:
// temporally-spread direct stores 6x write amp; round-8: global per-node
// atomics here regressed total — degree lives in k_bucket's LDS).
__global__ void __launch_bounds__(1024) k_scatter(const int4* __restrict__ src4,
                                                  const int4* __restrict__ dst4,
                                                  const float4* __restrict__ ew4,
                                                  unsigned int* __restrict__ cursor,
                                                  unsigned long long* __restrict__ part) {
    __shared__ unsigned int h[NBKT];
    __shared__ unsigned int gbase[NBKT];
    int tid = threadIdx.x, blk = blockIdx.x;
    for (int k = tid; k < NBKT; k += 1024) h[k] = 0u;
    __syncthreads();
    int q = blk * 1024 + tid;                  // one 4-edge group per thread
    bool v = (q < N_EDGES / 4);
    int4 ss = v ? src4[q] : make_int4(0, 0, 0, 0);
    int4 dd = v ? dst4[q] : make_int4(0, 0, 0, 0);
    float4 ww = v ? ew4[q] : make_float4(0.f, 0.f, 0.f, 0.f);
    int s[4] = { ss.x, ss.y, ss.z, ss.w };
    int d[4] = { dd.x, dd.y, dd.z, dd.w };
    float w[4] = { ww.x, ww.y, ww.z, ww.w };
    int bv[4]; unsigned int lr[4], lo[4], hiw[4];
    #pragma unroll
    for (int e = 0; e < 4; e++) {
        if (v) {
            int b = d[e] >> BKT_SH;
            bv[e] = b;
            lr[e] = atomicAdd(&h[b], 1u);      // native u32 ds_add
            lo[e] = ((unsigned int)(d[e] & (BKT_N - 1)) << 24) | (unsigned int)s[e];
            hiw[e] = __float_as_uint(w[e]);
        }
    }
    __syncthreads();
    for (int k = tid; k < NBKT; k += 1024) {
        unsigned int c = h[k];
        gbase[k] = c ? atomicAdd(&cursor[k], c) : 0u;
    }
    __syncthreads();
    if (v) {
        #pragma unroll
        for (int e = 0; e < 4; e++) {
            unsigned int off = gbase[bv[e]] + lr[e];
            if (off < SEG_CAP)  // 10-sigma margin; memory safety only
                part[(size_t)bv[e] * SEG_CAP + off] =
                    ((unsigned long long)hiw[e] << 32) | lo[e];
        }
    }
}

// ---- pass 2: per-bucket counting sort (rank-in-entry, no 2nd-pass atomics) ----
// cnt and degree PACKED in one u64 per node: one ds_add_u64 per edge returns
// rank (hi32) and accumulates 2^24 fixed-point degree (lo32; max 96*2^24 < 2^31
// so no carry into hi). Halves the hot-pass LDS atomic count vs round 10.
// (round-7: fp32 LDS atomics serialize ~14ns — u32/u64 native adds only.)
// Rowstarts 4-aligned (pad <=3/node, arena stride SEG_AL) so the gather reads
// csr rows with 16B uint4 loads. Pad slots are never read.
__global__ void __launch_bounds__(1024) k_bucket(const unsigned long long* __restrict__ part,
                                                 const unsigned int* __restrict__ cursor,
                                                 const float* __restrict__ x,
                                                 int2* __restrict__ offs2,
                                                 float* __restrict__ dinv_g,
                                                 uint4* __restrict__ xs,
                                                 unsigned int* __restrict__ csr4) {
    __shared__ uint2 stage[SEG_CAP];
    __shared__ unsigned long long cd[BKT_N];       // hi32 = count, lo32 = deg fx24
    __shared__ unsigned int cnt[BKT_N], rowstart[BKT_N], sc[BKT_N];
    __shared__ float dinv_l[BKT_N];
    int tid = threadIdx.x, k = blockIdx.x;
    unsigned int base = (unsigned int)k * SEG_CAP;       // part/stage index space
    unsigned int cbase = (unsigned int)k * SEG_AL;       // csr index space
    unsigned int m = cursor[k];
    if (m > SEG_CAP) m = SEG_CAP;
    if (tid < BKT_N) cd[tid] = (unsigned long long)(1u << 24);  // self loop weight 1.0
    __syncthreads();

    // histogram + rank + fixed-point degree: ONE ds_add_u64 per edge
    for (unsigned int i = tid; i < m; i += 1024) {
        unsigned long long p = __builtin_nontemporal_load(&part[base + i]);
        unsigned int lo = (unsigned int)p;
        unsigned int hi = (unsigned int)(p >> 32);
        unsigned int j = (lo >> 24) & (BKT_N - 1);
        unsigned long long inc = ((unsigned long long)1u << 32) |
                                 (unsigned long long)__float2uint_rn(__uint_as_float(hi) * DEG_SCALE);
        unsigned int r = (unsigned int)(atomicAdd(&cd[j], inc) >> 32);
        if (r > 255u) r = 255u;                 // impossible in practice; safety clamp
        stage[i] = make_uint2(lo | (r << 16), hi);   // bits[23:16] free (src < 2^16)
    }
    __syncthreads();
    if (tid < BKT_N) cnt[tid] = (unsigned int)(cd[tid] >> 32);
    __syncthreads();

    // wave-0 shfl prefix scan over 128 4-ALIGNED bucket counters (inclusive)
    if (tid < 64) {
        unsigned int a = (cnt[tid] + 3u) & ~3u;
        unsigned int b = (cnt[tid + 64] + 3u) & ~3u;
        unsigned int sa = a;
        #pragma unroll
        for (int off = 1; off < 64; off <<= 1) {
            unsigned int tv = __shfl_up(sa, off);
            if ((tid & 63) >= off) sa += tv;
        }
        unsigned int tot = __shfl(sa, 63);
        unsigned int sb = b;
        #pragma unroll
        for (int off = 1; off < 64; off <<= 1) {
            unsigned int tv = __shfl_up(sb, off);
            if ((tid & 63) >= off) sb += tv;
        }
        sc[tid] = sa;
        sc[tid + 64] = sb + tot;
    }
    __syncthreads();

    int n0 = k * BKT_N;
    int nn = N_NODES - n0; if (nn > BKT_N) nn = BKT_N;

    if (tid < BKT_N) {
        unsigned int ca = (cnt[tid] + 3u) & ~3u;
        unsigned int rs = sc[tid] - ca;         // 4-aligned row start
        rowstart[tid] = rs;
        float dv = rsqrtf((float)(unsigned int)cd[tid] * DEG_INV);
        dinv_l[tid] = dv;
        if (tid < nn) {
            dinv_g[n0 + tid] = dv;
            offs2[n0 + tid] = make_int2((int)(cbase + rs),
                                        (int)(cbase + rs + cnt[tid]));
        }
    }
    __syncthreads();

    // sorted write-out: slot = rowstart[j] + stored rank (no atomics)
    for (unsigned int i = tid; i < m; i += 1024) {
        uint2 vv = stage[i];
        unsigned int j = (vv.x >> 24) & (BKT_N - 1);
        unsigned int r = (vv.x >> 16) & 0xFFu;
        __half hw = __float2half(__uint_as_float(vv.y));
        unsigned int entry = ((unsigned int)__half_as_ushort(hw) << 16) |
                             (vv.x & 0xFFFFu);
        csr4[cbase + rowstart[j] + r] = entry;
    }

    // xs[n*6+c] = fp16(dinv[n] * x[n, 8c..8c+7])  (coalesced uint4)
    for (int idx = tid; idx < nn * 6; idx += 1024) {
        int j = idx / 6, c = idx % 6;
        float di = dinv_l[j];
        const float4* xr = (const float4*)(x + (size_t)(n0 + j) * FP + c * 8);
        float4 a = xr[0], b = xr[1];
        __half2 h0 = __floats2half2_rn(di * a.x, di * a.y);
        __half2 h1 = __floats2half2_rn(di * a.z, di * a.w);
        __half2 h2 = __floats2half2_rn(di * b.x, di * b.y);
        __half2 h3 = __floats2half2_rn(di * b.z, di * b.w);
        uint4 o;
        o.x = *(unsigned int*)&h0; o.y = *(unsigned int*)&h1;
        o.z = *(unsigned int*)&h2; o.w = *(unsigned int*)&h3;
        xs[(size_t)(n0 + j) * 6 + c] = o;
    }
}

// ---- pass 3: FUSED gather + epilogue. 192 threads = 8 nodes x 24 lanes ----
// TWO-PHASE gather: 24 lanes = 3 feature-chunks x 8 edge-groups per phase;
// phase 0 touches xs chunks 0-2 (2.4 MB), phase 1 chunks 3-5. Halves the
// instantaneous xs working set: 4.8 MB never fit the 4 MB per-XCD L2 (round-10
// FETCH 48.7 MB = table re-fetched ~10x). csr rows (~1 KB/block) are re-read
// in phase 1 -> PLAIN loads (NT would evict before the second pass).
// (round-9: 384-thread blocks hurt; keep 192.)
__global__ void __launch_bounds__(192) k_gnode(const uint4* __restrict__ xs,
                                               const float* __restrict__ dinv,
                                               const int2* __restrict__ offs2,
                                               const unsigned int* __restrict__ csr4,
                                               const float* __restrict__ att,
                                               const float* __restrict__ Wz,
                                               const float* __restrict__ bz,
                                               const float* __restrict__ Wh,
                                               const float* __restrict__ bh,
                                               const float* __restrict__ lzW,
                                               const float* __restrict__ lzb,
                                               const float* __restrict__ lhW,
                                               const float* __restrict__ lhb,
                                               const float* __restrict__ linW,
                                               const float* __restrict__ linb,
                                               float* __restrict__ out) {
    __shared__ float row[8][48];     // aggregated features, f-major (f*6+p)
    __shared__ float gzs[8][72];     // gz(p,kk) per node
    __shared__ float ghs[8][72];     // gh(p,kk) per node
    __shared__ float Hl[8][12];      // relu(H[j]) per node

    int tid = threadIdx.x;
    int L = tid / 24, r = tid % 24;
    int cl = r >> 3, g = r & 7;      // cl in 0..2 (chunk-local), g in 0..7 (edge-group)
    int n = blockIdx.x * 8 + L;      // 50000 = 6250 * 8, no tail

    int2 oe = offs2[n];
    const unsigned int* rowp = csr4 + oe.x;   // 16B-aligned (rowstarts 4-aligned)
    int cnt = oe.y - oe.x;
    float di = dinv[n];

    #pragma unroll
    for (int ph = 0; ph < 2; ph++) {
        int c = ph * 3 + cl;
        float a0 = 0.f, a1 = 0.f, a2 = 0.f, a3 = 0.f;
        float a4 = 0.f, a5 = 0.f, a6 = 0.f, a7 = 0.f;
        int kk = 0;
        for (; kk + 32 <= cnt; kk += 32) {
            u32x4 pc = *(const u32x4*)(rowp + kk + 4 * g);   // plain: L1/L2-hot for ph=1
            unsigned int p[4] = { pc.x, pc.y, pc.z, pc.w };
            uint4 v[4];
            #pragma unroll
            for (int u = 0; u < 4; u++)
                v[u] = xs[(size_t)(p[u] & 0xFFFFu) * 6 + c];
            #pragma unroll
            for (int u = 0; u < 4; u++) {
                float w = __half2float(__ushort_as_half((unsigned short)(p[u] >> 16)));
                float2 e0 = __half22float2(*(__half2*)&v[u].x);
                float2 e1 = __half22float2(*(__half2*)&v[u].y);
                float2 e2 = __half22float2(*(__half2*)&v[u].z);
                float2 e3 = __half22float2(*(__half2*)&v[u].w);
                a0 += w * e0.x; a1 += w * e0.y; a2 += w * e1.x; a3 += w * e1.y;
                a4 += w * e2.x; a5 += w * e2.y; a6 += w * e3.x; a7 += w * e3.y;
            }
        }
        // tail: lane g covers [kk+4g, kk+4g+4) clipped to cnt (union covers [kk,cnt))
        int tlo = kk + 4 * g, thi = tlo + 4; if (thi > cnt) thi = cnt;
        for (int jj = tlo; jj < thi; jj++) {
            unsigned int p = rowp[jj];
            float w = __half2float(__ushort_as_half((unsigned short)(p >> 16)));
            uint4 v = xs[(size_t)(p & 0xFFFFu) * 6 + c];
            float2 e0 = __half22float2(*(__half2*)&v.x);
            float2 e1 = __half22float2(*(__half2*)&v.y);
            float2 e2 = __half22float2(*(__half2*)&v.z);
            float2 e3 = __half22float2(*(__half2*)&v.w);
            a0 += w * e0.x; a1 += w * e0.y; a2 += w * e1.x; a3 += w * e1.y;
            a4 += w * e2.x; a5 += w * e2.y; a6 += w * e3.x; a7 += w * e3.y;
        }
        // combine the 8 edge-groups (t^1, t^2, t^4): 8-blocks are 8-aligned since
        // tid = L*24 + cl*8 + g = 8*(3L+cl)+g, and 8 | 64 -> never straddle a wave
        a0 += __shfl_xor(a0, 1); a1 += __shfl_xor(a1, 1);
        a2 += __shfl_xor(a2, 1); a3 += __shfl_xor(a3, 1);
        a4 += __shfl_xor(a4, 1); a5 += __shfl_xor(a5, 1);
        a6 += __shfl_xor(a6, 1); a7 += __shfl_xor(a7, 1);
        a0 += __shfl_xor(a0, 2); a1 += __shfl_xor(a1, 2);
        a2 += __shfl_xor(a2, 2); a3 += __shfl_xor(a3, 2);
        a4 += __shfl_xor(a4, 2); a5 += __shfl_xor(a5, 2);
        a6 += __shfl_xor(a6, 2); a7 += __shfl_xor(a7, 2);
        a0 += __shfl_xor(a0, 4); a1 += __shfl_xor(a1, 4);
        a2 += __shfl_xor(a2, 4); a3 += __shfl_xor(a3, 4);
        a4 += __shfl_xor(a4, 4); a5 += __shfl_xor(a5, 4);
        a6 += __shfl_xor(a6, 4); a7 += __shfl_xor(a7, 4);
        if (g == 0) {
            uint4 sf = xs[(size_t)n * 6 + c];  // self loop (dinv[n]*x already folded)
            float2 s0 = __half22float2(*(__half2*)&sf.x);
            float2 s1 = __half22float2(*(__half2*)&sf.y);
            float2 s2 = __half22float2(*(__half2*)&sf.z);
            float2 s3 = __half22float2(*(__half2*)&sf.w);
            row[L][8 * c + 0] = di * (a0 + s0.x); row[L][8 * c + 1] = di * (a1 + s0.y);
            row[L][8 * c + 2] = di * (a2 + s1.x); row[L][8 * c + 3] = di * (a3 + s1.y);
            row[L][8 * c + 4] = di * (a4 + s2.x); row[L][8 * c + 5] = di * (a5 + s2.y);
            row[L][8 * c + 6] = di * (a6 + s3.x); row[L][8 * c + 7] = di * (a7 + s3.y);
        }
    }
    __syncthreads();

    // ---- phase A: gz/gh(p,kk) = b[kk] + sum_f row[f*6+p] * W[f*12+kk] ----
    for (int it = r; it < 72; it += 24) {
        int p = it / 12, q = it - p * 12;
        float gz = bz[q], gh = bh[q];
        #pragma unroll
        for (int f = 0; f < F_IN; f++) {
            float xv = row[L][f * 6 + p];
            gz += xv * Wz[f * F_OUT + q];
            gh += xv * Wh[f * F_OUT + q];
        }
        gzs[L][it] = gz; ghs[L][it] = gh;
    }
    __syncthreads();

    // ---- phase B: 12 j-lanes/node: H[j] over 6 periods ----
    if (r < 12) {
        float a[PERIODS];
        float mx = -1e30f;
        #pragma unroll
        for (int p = 0; p < PERIODS; p++) { a[p] = att[p]; mx = fmaxf(mx, a[p]); }
        float se = 0.f;
        #pragma unroll
        for (int p = 0; p < PERIODS; p++) { a[p] = __expf(a[p] - mx); se += a[p]; }
        float inv = 1.f / se;
        int j = r;
        float hacc = 0.f;
        #pragma unroll
        for (int p = 0; p < PERIODS; p++) {
            float z = lzb[j], t2 = lhb[j];
            #pragma unroll
            for (int q = 0; q < F_OUT; q++) {
                z  += gzs[L][p * 12 + q] * lzW[j * (2 * F_OUT) + q];
                t2 += ghs[L][p * 12 + q] * lhW[j * (2 * F_OUT) + q];
            }
            float Z = 1.f / (1.f + __expf(-z));
            // fast tanh: 1 - 2/(e^{2x}+1); saturates correctly for |x| large
            float e2 = __expf(2.f * t2);
            float th = 1.f - __fdividef(2.f, e2 + 1.f);
            hacc += (a[p] * inv) * (1.f - Z) * th;
        }
        Hl[L][j] = fmaxf(hacc, 0.f);           // relu fused here
    }
    __syncthreads();

    // ---- phase C: 6 q-lanes/node: out = linb + relu(H) @ linW^T ----
    if (r < PERIODS) {
        float acc = linb[r];
        #pragma unroll
        for (int j = 0; j < F_OUT; j++)
            acc += Hl[L][j] * linW[r * F_OUT + j];
        out[(size_t)n * PERIODS + r] = acc;
    }
}

extern "C" void kernel_launch(void* const* d_in, const int* in_sizes, int n_in,
                              void* d_out, int out_size, void* d_ws, size_t ws_size,
                              hipStream_t stream) {
    const float* x    = (const float*)d_in[0];
    const int*   ei   = (const int*)d_in[1];
    const float* ew   = (const float*)d_in[2];
    const float* att  = (const float*)d_in[3];
    const float* Wz   = (const float*)d_in[4];
    const float* bz   = (const float*)d_in[5];
    // d_in[6]=Wr, d_in[7]=br : dead (H0 == 0)
    const float* Wh   = (const float*)d_in[8];
    const float* bh   = (const float*)d_in[9];
    const float* lzW  = (const float*)d_in[10];
    const float* lzb  = (const float*)d_in[11];
    // d_in[12]=lrW, d_in[13]=lrb : dead
    const float* lhW  = (const float*)d_in[14];
    const float* lhb  = (const float*)d_in[15];
    const float* linW = (const float*)d_in[16];
    const float* linb = (const float*)d_in[17];
    float* out = (float*)d_out;

    // ws layout (~28.5 MB): xs (16B-aligned first), part, csr4, offs2, dinv, cursor
    uint4* xs   = (uint4*)d_ws;                                   // N*6 uint4 = 4.8 MB
    unsigned long long* part = (unsigned long long*)(xs + (size_t)N_NODES * 6);   // 14.8 MB
    unsigned int* csr4 = (unsigned int*)(part + (size_t)NBKT * SEG_CAP);          // 8.0 MB
    int2*  offs2 = (int2*)(csr4 + (size_t)NBKT * SEG_AL);         // N int2
    float* dinv  = (float*)(offs2 + N_NODES);                     // N f32
    unsigned int* cursor = (unsigned int*)(dinv + N_NODES);       // NBKT u32

    const int* srcp = ei;
    const int* dstp = ei + N_EDGES;

    // cursor zero via stream memset (drops the k_zero dispatch boundary)
    hipMemsetAsync(cursor, 0, NBKT * sizeof(unsigned int), stream);
    k_scatter<<<NCHK, 1024, 0, stream>>>((const int4*)srcp, (const int4*)dstp,
                                         (const float4*)ew, cursor, part);
    k_bucket<<<NBKT, 1024, 0, stream>>>(part, cursor, x, offs2, dinv, xs, csr4);
    k_gnode<<<N_NODES / 8, 192, 0, stream>>>(xs, dinv, offs2, csr4, att,
                                             Wz, bz, Wh, bh, lzW, lzb, lhW, lhb,
                                             linW, linb, out);
}

// Round 13
// 179.679 us; speedup vs baseline: 1.0433x; 1.0433x over previous
//
#include <hip/hip_runtime.h>
#include <hip/hip_fp16.h>

#define N_NODES 50000
#define N_EDGES 1600000
#define F_IN 8
#define F_OUT 12
#define PERIODS 6
#define FP 48                      // F_IN * PERIODS
#define BKT_SH 7                   // 128 nodes per bucket
#define BKT_N 128
#define NBKT ((N_NODES + BKT_N - 1) / BKT_N)   // 391
#define CHK 4096                   // edges per scatter block (4/thread at 1024 threads)
#define NCHK ((N_EDGES + CHK - 1) / CHK)       // 391
#define SEG_CAP 4736               // per-bucket part/stage capacity (mean 4092, +10 sigma)
#define SEG_AL  5120               // per-bucket csr stride: 4736 + 128*3 (4-align pad, exact)
#define DEG_SCALE 16777216.0f      // 2^24 fixed point for degree (u32 low word)
#define DEG_INV   5.9604644775390625e-8f

typedef unsigned int u32x4 __attribute__((ext_vector_type(4)));

// ---- pass 1: fused histogram + reservation + scatter (bucketed) ----
// part entry: hi32 = fp32 ew bits, lo32 = (dlocal&127)<<24 | src   (src < 2^16)
// PLAIN stores: per-(block,bucket) runs assemble into full lines in the writer's
// L2 within one block's burst (round-2: NT stores 6.5x write amp; round-5:
// temporally-spread direct stores 6x write amp; round-8: global per-node
// atomics here regressed total; round-12: cross-XCD handoff MUST cross a
// kernel boundary — per-XCD L2s are not coherent, grid.sync is not enough).
__global__ void __launch_bounds__(1024) k_scatter(const int4* __restrict__ src4,
                                                  const int4* __restrict__ dst4,
                                                  const float4* __restrict__ ew4,
                                                  unsigned int* __restrict__ cursor,
                                                  unsigned long long* __restrict__ part) {
    __shared__ unsigned int h[NBKT];
    __shared__ unsigned int gbase[NBKT];
    int tid = threadIdx.x, blk = blockIdx.x;
    for (int k = tid; k < NBKT; k += 1024) h[k] = 0u;
    __syncthreads();
    int q = blk * 1024 + tid;                  // one 4-edge group per thread
    bool v = (q < N_EDGES / 4);
    int4 ss = v ? src4[q] : make_int4(0, 0, 0, 0);
    int4 dd = v ? dst4[q] : make_int4(0, 0, 0, 0);
    float4 ww = v ? ew4[q] : make_float4(0.f, 0.f, 0.f, 0.f);
    int s[4] = { ss.x, ss.y, ss.z, ss.w };
    int d[4] = { dd.x, dd.y, dd.z, dd.w };
    float w[4] = { ww.x, ww.y, ww.z, ww.w };
    int bv[4]; unsigned int lr[4], lo[4], hiw[4];
    #pragma unroll
    for (int e = 0; e < 4; e++) {
        if (v) {
            int b = d[e] >> BKT_SH;
            bv[e] = b;
            lr[e] = atomicAdd(&h[b], 1u);      // native u32 ds_add
            lo[e] = ((unsigned int)(d[e] & (BKT_N - 1)) << 24) | (unsigned int)s[e];
            hiw[e] = __float_as_uint(w[e]);
        }
    }
    __syncthreads();
    for (int k = tid; k < NBKT; k += 1024) {
        unsigned int c = h[k];
        gbase[k] = c ? atomicAdd(&cursor[k], c) : 0u;
    }
    __syncthreads();
    if (v) {
        #pragma unroll
        for (int e = 0; e < 4; e++) {
            unsigned int off = gbase[bv[e]] + lr[e];
            if (off < SEG_CAP)  // 10-sigma margin; memory safety only
                part[(size_t)bv[e] * SEG_CAP + off] =
                    ((unsigned long long)hiw[e] << 32) | lo[e];
        }
    }
}

// ---- pass 2: per-bucket counting sort (rank-in-entry, no 2nd-pass atomics) ----
// cnt and degree PACKED in one u64 per node: one ds_add_u64 per edge returns
// rank (hi32) and accumulates 2^24 fixed-point degree (lo32; max 96*2^24 < 2^31
// so no carry into hi). (round-7: fp32 LDS atomics serialize ~14ns — native
// u32/u64 adds only.) Rowstarts 4-aligned (pad <=3/node, arena stride SEG_AL)
// so the gather reads csr rows with 16B uint4 loads. Pad slots never read.
__global__ void __launch_bounds__(1024) k_bucket(const unsigned long long* __restrict__ part,
                                                 const unsigned int* __restrict__ cursor,
                                                 const float* __restrict__ x,
                                                 int2* __restrict__ offs2,
                                                 float* __restrict__ dinv_g,
                                                 uint4* __restrict__ xs,
                                                 unsigned int* __restrict__ csr4) {
    __shared__ uint2 stage[SEG_CAP];
    __shared__ unsigned long long cd[BKT_N];       // hi32 = count, lo32 = deg fx24
    __shared__ unsigned int cnt[BKT_N], rowstart[BKT_N], sc[BKT_N];
    __shared__ float dinv_l[BKT_N];
    int tid = threadIdx.x, k = blockIdx.x;
    unsigned int base = (unsigned int)k * SEG_CAP;       // part/stage index space
    unsigned int cbase = (unsigned int)k * SEG_AL;       // csr index space
    unsigned int m = cursor[k];
    if (m > SEG_CAP) m = SEG_CAP;
    if (tid < BKT_N) cd[tid] = (unsigned long long)(1u << 24);  // self loop weight 1.0
    __syncthreads();

    // histogram + rank + fixed-point degree: ONE ds_add_u64 per edge
    for (unsigned int i = tid; i < m; i += 1024) {
        unsigned long long p = __builtin_nontemporal_load(&part[base + i]);
        unsigned int lo = (unsigned int)p;
        unsigned int hi = (unsigned int)(p >> 32);
        unsigned int j = (lo >> 24) & (BKT_N - 1);
        unsigned long long inc = ((unsigned long long)1u << 32) |
                                 (unsigned long long)__float2uint_rn(__uint_as_float(hi) * DEG_SCALE);
        unsigned int r = (unsigned int)(atomicAdd(&cd[j], inc) >> 32);
        if (r > 255u) r = 255u;                 // impossible in practice; safety clamp
        stage[i] = make_uint2(lo | (r << 16), hi);   // bits[23:16] free (src < 2^16)
    }
    __syncthreads();
    if (tid < BKT_N) cnt[tid] = (unsigned int)(cd[tid] >> 32);
    __syncthreads();

    // wave-0 shfl prefix scan over 128 4-ALIGNED bucket counters (inclusive)
    if (tid < 64) {
        unsigned int a = (cnt[tid] + 3u) & ~3u;
        unsigned int b = (cnt[tid + 64] + 3u) & ~3u;
        unsigned int sa = a;
        #pragma unroll
        for (int off = 1; off < 64; off <<= 1) {
            unsigned int tv = __shfl_up(sa, off);
            if ((tid & 63) >= off) sa += tv;
        }
        unsigned int tot = __shfl(sa, 63);
        unsigned int sb = b;
        #pragma unroll
        for (int off = 1; off < 64; off <<= 1) {
            unsigned int tv = __shfl_up(sb, off);
            if ((tid & 63) >= off) sb += tv;
        }
        sc[tid] = sa;
        sc[tid + 64] = sb + tot;
    }
    __syncthreads();

    int n0 = k * BKT_N;
    int nn = N_NODES - n0; if (nn > BKT_N) nn = BKT_N;

    if (tid < BKT_N) {
        unsigned int ca = (cnt[tid] + 3u) & ~3u;
        unsigned int rs = sc[tid] - ca;         // 4-aligned row start
        rowstart[tid] = rs;
        float dv = rsqrtf((float)(unsigned int)cd[tid] * DEG_INV);
        dinv_l[tid] = dv;
        if (tid < nn) {
            dinv_g[n0 + tid] = dv;
            offs2[n0 + tid] = make_int2((int)(cbase + rs),
                                        (int)(cbase + rs + cnt[tid]));
        }
    }
    __syncthreads();

    // sorted write-out: slot = rowstart[j] + stored rank (no atomics)
    for (unsigned int i = tid; i < m; i += 1024) {
        uint2 vv = stage[i];
        unsigned int j = (vv.x >> 24) & (BKT_N - 1);
        unsigned int r = (vv.x >> 16) & 0xFFu;
        __half hw = __float2half(__uint_as_float(vv.y));
        unsigned int entry = ((unsigned int)__half_as_ushort(hw) << 16) |
                             (vv.x & 0xFFFFu);
        csr4[cbase + rowstart[j] + r] = entry;
    }

    // xs[n*6+c] = fp16(dinv[n] * x[n, 8c..8c+7])  (coalesced uint4)
    for (int idx = tid; idx < nn * 6; idx += 1024) {
        int j = idx / 6, c = idx % 6;
        float di = dinv_l[j];
        const float4* xr = (const float4*)(x + (size_t)(n0 + j) * FP + c * 8);
        float4 a = xr[0], b = xr[1];
        __half2 h0 = __floats2half2_rn(di * a.x, di * a.y);
        __half2 h1 = __floats2half2_rn(di * a.z, di * a.w);
        __half2 h2 = __floats2half2_rn(di * b.x, di * b.y);
        __half2 h3 = __floats2half2_rn(di * b.z, di * b.w);
        uint4 o;
        o.x = *(unsigned int*)&h0; o.y = *(unsigned int*)&h1;
        o.z = *(unsigned int*)&h2; o.w = *(unsigned int*)&h3;
        xs[(size_t)(n0 + j) * 6 + c] = o;
    }
}

// ---- pass 3: FUSED gather + epilogue. 192 threads = 8 nodes x 24 lanes ----
// (round-6 structure; round-9: 384-thread blocks hurt; round-11: chunk-split
// breaks xs line locality — single pass, 6 chunks x 4 groups.)
// NEW: csr index load SOFTWARE-PIPELINED one macro-iter ahead — removes the
// ~200cy L2 index-load latency from the per-iter dependent chain
// (idx -> 4 xs gathers -> FMA). Over-read past row end lands in the padded
// csr arena / adjacent ws (mapped, never used) — loads are junk-safe.
__global__ void __launch_bounds__(192) k_gnode(const uint4* __restrict__ xs,
                                               const float* __restrict__ dinv,
                                               const int2* __restrict__ offs2,
                                               const unsigned int* __restrict__ csr4,
                                               const float* __restrict__ att,
                                               const float* __restrict__ Wz,
                                               const float* __restrict__ bz,
                                               const float* __restrict__ Wh,
                                               const float* __restrict__ bh,
                                               const float* __restrict__ lzW,
                                               const float* __restrict__ lzb,
                                               const float* __restrict__ lhW,
                                               const float* __restrict__ lhb,
                                               const float* __restrict__ linW,
                                               const float* __restrict__ linb,
                                               float* __restrict__ out) {
    __shared__ float row[8][48];     // aggregated features, f-major (f*6+p)
    __shared__ float gzs[8][72];     // gz(p,kk) per node
    __shared__ float ghs[8][72];     // gh(p,kk) per node
    __shared__ float Hl[8][12];      // relu(H[j]) per node

    int tid = threadIdx.x;
    int L = tid / 24, r = tid % 24, c = r >> 2, g = r & 3;
    int n = blockIdx.x * 8 + L;      // 50000 = 6250 * 8, no tail

    // ---- gather phase ----
    int2 oe = offs2[n];
    const unsigned int* rowp = csr4 + oe.x;   // 16B-aligned (rowstarts 4-aligned)
    int cnt = oe.y - oe.x;
    float a0 = 0.f, a1 = 0.f, a2 = 0.f, a3 = 0.f;
    float a4 = 0.f, a5 = 0.f, a6 = 0.f, a7 = 0.f;
    int kk = 0;
    // prefetch iter-0 indices (junk-safe if cnt < 16: unused)
    u32x4 pc = __builtin_nontemporal_load((const u32x4*)(rowp + 4 * g));
    for (; kk + 16 <= cnt; kk += 16) {
        u32x4 pcn = __builtin_nontemporal_load((const u32x4*)(rowp + kk + 16 + 4 * g));
        unsigned int p[4] = { pc.x, pc.y, pc.z, pc.w };
        uint4 v[4];
        #pragma unroll
        for (int u = 0; u < 4; u++)
            v[u] = xs[(size_t)(p[u] & 0xFFFFu) * 6 + c];
        #pragma unroll
        for (int u = 0; u < 4; u++) {
            float w = __half2float(__ushort_as_half((unsigned short)(p[u] >> 16)));
            float2 e0 = __half22float2(*(__half2*)&v[u].x);
            float2 e1 = __half22float2(*(__half2*)&v[u].y);
            float2 e2 = __half22float2(*(__half2*)&v[u].z);
            float2 e3 = __half22float2(*(__half2*)&v[u].w);
            a0 += w * e0.x; a1 += w * e0.y; a2 += w * e1.x; a3 += w * e1.y;
            a4 += w * e2.x; a5 += w * e2.y; a6 += w * e3.x; a7 += w * e3.y;
        }
        pc = pcn;
    }
    // tail: lanes g cover [kk+4g, kk+4g+4) clipped to cnt (union covers [kk,cnt))
    int tlo = kk + 4 * g, thi = tlo + 4; if (thi > cnt) thi = cnt;
    for (int jj = tlo; jj < thi; jj++) {
        unsigned int p = __builtin_nontemporal_load(rowp + jj);
        float w = __half2float(__ushort_as_half((unsigned short)(p >> 16)));
        uint4 v = xs[(size_t)(p & 0xFFFFu) * 6 + c];
        float2 e0 = __half22float2(*(__half2*)&v.x);
        float2 e1 = __half22float2(*(__half2*)&v.y);
        float2 e2 = __half22float2(*(__half2*)&v.z);
        float2 e3 = __half22float2(*(__half2*)&v.w);
        a0 += w * e0.x; a1 += w * e0.y; a2 += w * e1.x; a3 += w * e1.y;
        a4 += w * e2.x; a5 += w * e2.y; a6 += w * e3.x; a7 += w * e3.y;
    }
    // combine the 4 edge-groups (partners t^1, t^2: 4-blocks are 4-aligned,
    // never straddle a wave: tid = L*24 + c*4 + g)
    a0 += __shfl_xor(a0, 1); a1 += __shfl_xor(a1, 1);
    a2 += __shfl_xor(a2, 1); a3 += __shfl_xor(a3, 1);
    a4 += __shfl_xor(a4, 1); a5 += __shfl_xor(a5, 1);
    a6 += __shfl_xor(a6, 1); a7 += __shfl_xor(a7, 1);
    a0 += __shfl_xor(a0, 2); a1 += __shfl_xor(a1, 2);
    a2 += __shfl_xor(a2, 2); a3 += __shfl_xor(a3, 2);
    a4 += __shfl_xor(a4, 2); a5 += __shfl_xor(a5, 2);
    a6 += __shfl_xor(a6, 2); a7 += __shfl_xor(a7, 2);
    if (g == 0) {
        uint4 sf = xs[(size_t)n * 6 + c];      // self loop (dinv[n]*x already folded)
        float2 s0 = __half22float2(*(__half2*)&sf.x);
        float2 s1 = __half22float2(*(__half2*)&sf.y);
        float2 s2 = __half22float2(*(__half2*)&sf.z);
        float2 s3 = __half22float2(*(__half2*)&sf.w);
        float di = dinv[n];
        row[L][8 * c + 0] = di * (a0 + s0.x); row[L][8 * c + 1] = di * (a1 + s0.y);
        row[L][8 * c + 2] = di * (a2 + s1.x); row[L][8 * c + 3] = di * (a3 + s1.y);
        row[L][8 * c + 4] = di * (a4 + s2.x); row[L][8 * c + 5] = di * (a5 + s2.y);
        row[L][8 * c + 6] = di * (a6 + s3.x); row[L][8 * c + 7] = di * (a7 + s3.y);
    }
    __syncthreads();

    // ---- phase A: gz/gh(p,kk) = b[kk] + sum_f row[f*6+p] * W[f*12+kk] ----
    for (int it = r; it < 72; it += 24) {
        int p = it / 12, q = it - p * 12;
        float gz = bz[q], gh = bh[q];
        #pragma unroll
        for (int f = 0; f < F_IN; f++) {
            float xv = row[L][f * 6 + p];
            gz += xv * Wz[f * F_OUT + q];
            gh += xv * Wh[f * F_OUT + q];
        }
        gzs[L][it] = gz; ghs[L][it] = gh;
    }
    __syncthreads();

    // ---- phase B: 12 j-lanes/node: H[j] over 6 periods ----
    if (r < 12) {
        float a[PERIODS];
        float mx = -1e30f;
        #pragma unroll
        for (int p = 0; p < PERIODS; p++) { a[p] = att[p]; mx = fmaxf(mx, a[p]); }
        float se = 0.f;
        #pragma unroll
        for (int p = 0; p < PERIODS; p++) { a[p] = __expf(a[p] - mx); se += a[p]; }
        float inv = 1.f / se;
        int j = r;
        float hacc = 0.f;
        #pragma unroll
        for (int p = 0; p < PERIODS; p++) {
            float z = lzb[j], t2 = lhb[j];
            #pragma unroll
            for (int q = 0; q < F_OUT; q++) {
                z  += gzs[L][p * 12 + q] * lzW[j * (2 * F_OUT) + q];
                t2 += ghs[L][p * 12 + q] * lhW[j * (2 * F_OUT) + q];
            }
            float Z = 1.f / (1.f + __expf(-z));
            // fast tanh: 1 - 2/(e^{2x}+1); saturates correctly for |x| large
            float e2 = __expf(2.f * t2);
            float th = 1.f - __fdividef(2.f, e2 + 1.f);
            hacc += (a[p] * inv) * (1.f - Z) * th;
        }
        Hl[L][j] = fmaxf(hacc, 0.f);           // relu fused here
    }
    __syncthreads();

    // ---- phase C: 6 q-lanes/node: out = linb + relu(H) @ linW^T ----
    if (r < PERIODS) {
        float acc = linb[r];
        #pragma unroll
        for (int j = 0; j < F_OUT; j++)
            acc += Hl[L][j] * linW[r * F_OUT + j];
        out[(size_t)n * PERIODS + r] = acc;
    }
}

extern "C" void kernel_launch(void* const* d_in, const int* in_sizes, int n_in,
                              void* d_out, int out_size, void* d_ws, size_t ws_size,
                              hipStream_t stream) {
    const float* x    = (const float*)d_in[0];
    const int*   ei   = (const int*)d_in[1];
    const float* ew   = (const float*)d_in[2];
    const float* att  = (const float*)d_in[3];
    const float* Wz   = (const float*)d_in[4];
    const float* bz   = (const float*)d_in[5];
    // d_in[6]=Wr, d_in[7]=br : dead (H0 == 0)
    const float* Wh   = (const float*)d_in[8];
    const float* bh   = (const float*)d_in[9];
    const float* lzW  = (const float*)d_in[10];
    const float* lzb  = (const float*)d_in[11];
    // d_in[12]=lrW, d_in[13]=lrb : dead
    const float* lhW  = (const float*)d_in[14];
    const float* lhb  = (const float*)d_in[15];
    const float* linW = (const float*)d_in[16];
    const float* linb = (const float*)d_in[17];
    float* out = (float*)d_out;

    // ws layout (~28.5 MB): xs (16B-aligned first), part, csr4, offs2, dinv, cursor
    uint4* xs   = (uint4*)d_ws;                                   // N*6 uint4 = 4.8 MB
    unsigned long long* part = (unsigned long long*)(xs + (size_t)N_NODES * 6);   // 14.8 MB
    unsigned int* csr4 = (unsigned int*)(part + (size_t)NBKT * SEG_CAP);          // 8.0 MB
    int2*  offs2 = (int2*)(csr4 + (size_t)NBKT * SEG_AL);         // N int2
    float* dinv  = (float*)(offs2 + N_NODES);                     // N f32
    unsigned int* cursor = (unsigned int*)(dinv + N_NODES);       // NBKT u32

    const int* srcp = ei;
    const int* dstp = ei + N_EDGES;

    // cursor zero via stream memset (drops the k_zero dispatch boundary)
    hipMemsetAsync(cursor, 0, NBKT * sizeof(unsigned int), stream);
    k_scatter<<<NCHK, 1024, 0, stream>>>((const int4*)srcp, (const int4*)dstp,
                                         (const float4*)ew, cursor, part);
    k_bucket<<<NBKT, 1024, 0, stream>>>(part, cursor, x, offs2, dinv, xs, csr4);
    k_gnode<<<N_NODES / 8, 192, 0, stream>>>(xs, dinv, offs2, csr4, att,
                                             Wz, bz, Wh, bh, lzW, lzb, lhW, lhb,
                                             linW, linb, out);
}